// Round 9
// baseline (10512.251 us; speedup 1.0000x reference)
//
#include <hip/hip_runtime.h>
#include <cstdint>
#include <cstddef>

typedef _Float16 f16;
typedef _Float16 f16x8 __attribute__((ext_vector_type(8)));
typedef float f32x4 __attribute__((ext_vector_type(4)));

#define MFMA_F16(a,b,c) __builtin_amdgcn_mfma_f32_16x16x32_f16((a),(b),(c),0,0,0)

#define LOG2E  1.4426950408889634f
#define LOG2E2 2.885390081777927f

__device__ __forceinline__ float sigf(float x){
  return __builtin_amdgcn_rcpf(1.f + exp2f(-x * LOG2E));
}
__device__ __forceinline__ float tanhfast(float x){
  float e = exp2f(x * LOG2E2);
  return fmaf(-2.f, __builtin_amdgcn_rcpf(e + 1.f), 1.f);
}

__device__ __forceinline__ void st_wt_f32(float* p, float v){
  asm volatile("global_store_dword %0, %1, off sc0 sc1" :: "v"(p), "v"(v) : "memory");
}
__device__ __forceinline__ void st_wt_u32(f16* p, unsigned v){
  asm volatile("global_store_dword %0, %1, off sc0 sc1" :: "v"(p), "v"(v) : "memory");
}
__device__ __forceinline__ void st_tag(unsigned* p, unsigned v){
  asm volatile("global_store_dword %0, %1, off sc0 sc1" :: "v"(p), "v"(v) : "memory");
}
__device__ __forceinline__ void tag_wait(const unsigned* p, unsigned target){
  for (;;){
    unsigned v;
    asm volatile("global_load_dword %0, %1, off sc0 sc1\n\ts_waitcnt vmcnt(0)"
                 : "=v"(v) : "v"(p) : "memory");
    if (v >= target) return;
    __builtin_amdgcn_s_sleep(1);
  }
}
__device__ __forceinline__ void vm_drain(){ asm volatile("s_waitcnt vmcnt(0)" ::: "memory"); }

template<int N> __device__ __forceinline__ void vm_waitN(){
  asm volatile("s_waitcnt vmcnt(%0)" :: "i"(N) : "memory");
  __builtin_amdgcn_sched_barrier(0);
}

// Coherent read of 8 consecutive f32 (one 32B slice of a z row).
__device__ __forceinline__ void ld_8f32(const float* p, f32x4& a, f32x4& b){
  asm volatile(
    "global_load_dwordx4 %0, %2, off sc0 sc1\n\t"
    "global_load_dwordx4 %1, %2, off offset:16 sc0 sc1\n\t"
    "s_waitcnt vmcnt(0)"
    : "=&v"(a), "=&v"(b) : "v"(p) : "memory");
}

// Coherent batched ISSUE (no wait) of 8 consecutive 64B k-chunks of one row.
__device__ __forceinline__ void ld8_issue(const f16* p, f16x8* f){
  asm volatile(
    "global_load_dwordx4 %0, %8, off sc0 sc1\n\t"
    "global_load_dwordx4 %1, %8, off offset:64 sc0 sc1\n\t"
    "global_load_dwordx4 %2, %8, off offset:128 sc0 sc1\n\t"
    "global_load_dwordx4 %3, %8, off offset:192 sc0 sc1\n\t"
    "global_load_dwordx4 %4, %8, off offset:256 sc0 sc1\n\t"
    "global_load_dwordx4 %5, %8, off offset:320 sc0 sc1\n\t"
    "global_load_dwordx4 %6, %8, off offset:384 sc0 sc1\n\t"
    "global_load_dwordx4 %7, %8, off offset:448 sc0 sc1"
    : "=&v"(f[0]),"=&v"(f[1]),"=&v"(f[2]),"=&v"(f[3]),
      "=&v"(f[4]),"=&v"(f[5]),"=&v"(f[6]),"=&v"(f[7])
    : "v"(p) : "memory");
}

// 32-row x 32-col x K=512 GEMM slice (one k-half). A rows coherent, 16 loads
// issued up front, ONE intermediate counted wait; B frags in registers.
__device__ __forceinline__ f32x4 gemm16(const f16* hp, const f16x8* bfrag){
  f32x4 a = {0.f,0.f,0.f,0.f};
  f16x8 fA[8], fB[8];
  ld8_issue(hp,       fA);
  ld8_issue(hp + 256, fB);
  vm_waitN<8>();
  #pragma unroll
  for (int kk = 0; kk < 8; ++kk) a = MFMA_F16(fA[kk], bfrag[kk], a);
  vm_waitN<0>();
  #pragma unroll
  for (int kk = 0; kk < 8; ++kk) a = MFMA_F16(fB[kk], bfrag[8 + kk], a);
  return a;
}

// ---------------------------------------------------------------------------
__global__ __launch_bounds__(256) void k_transpose_f16(const float* __restrict__ src,
    f16* __restrict__ dst, int K, int N, int dstStride, int dstOff){
  const int n0 = blockIdx.x*32, k0 = blockIdx.y*32, tid = threadIdx.x;
  __shared__ float tl[32][33];
  #pragma unroll
  for (int rep = 0; rep < 4; ++rep){
    int e = rep*256 + tid; int i = e >> 5, j = e & 31;
    int k = k0 + i, n = n0 + j;
    tl[i][j] = (k < K && n < N) ? src[(size_t)k*N + n] : 0.f;
  }
  __syncthreads();
  #pragma unroll
  for (int rep = 0; rep < 4; ++rep){
    int e = rep*256 + tid; int i2 = e & 31, j2 = e >> 5;
    int n = n0 + j2, k = k0 + i2;
    if (k < K && n < N) dst[(size_t)n*dstStride + dstOff + k] = (f16)tl[i2][j2];
  }
}

// ---------------------------------------------------------------------------
__global__ __launch_bounds__(256) void k_prenet(const float* __restrict__ dec,
    const float* __restrict__ w1, const float* __restrict__ w2, f16* __restrict__ cellin){
  const int t = blockIdx.x, tid = threadIdx.x;
  __shared__ float sin_[32][81];
  __shared__ f16   w1T[256][88];
  __shared__ float x1s[32][260];
  __shared__ f16   w2c[256][72];
  __shared__ f16   xo[32][256];
  for (int e = tid; e < 32*80; e += 256){
    int i = e/80, m = e - i*80;
    sin_[i][m] = (t == 0) ? 0.f : dec[(size_t)i*61440 + (size_t)m*768 + (t-1)];
  }
  for (int e = tid; e < 80*256; e += 256){ int m = e >> 8, j = e & 255; w1T[j][m] = (f16)w1[e]; }
  __syncthreads();
  const int j = tid;
  for (int i = 0; i < 32; ++i){
    float a = 0.f;
    #pragma unroll
    for (int m8 = 0; m8 < 10; ++m8){
      f16x8 wvv = *(const f16x8*)&w1T[j][m8*8];
      #pragma unroll
      for (int l = 0; l < 8; ++l) a += (float)wvv[l] * sin_[i][m8*8 + l];
    }
    x1s[i][j] = fmaxf(a, 0.f);
  }
  __syncthreads();
  float acc2[32];
  #pragma unroll
  for (int i = 0; i < 32; ++i) acc2[i] = 0.f;
  for (int c = 0; c < 4; ++c){
    for (int e = tid; e < 64*256; e += 256){
      int kl = e >> 8, jj = e & 255;
      w2c[jj][kl] = (f16)w2[(size_t)(c*64 + kl)*256 + jj];
    }
    __syncthreads();
    f16x8 wv8[8];
    #pragma unroll
    for (int k8 = 0; k8 < 8; ++k8) wv8[k8] = *(const f16x8*)&w2c[j][k8*8];
    for (int i = 0; i < 32; ++i){
      float a = 0.f;
      #pragma unroll
      for (int k8 = 0; k8 < 8; ++k8)
        #pragma unroll
        for (int l = 0; l < 8; ++l) a += (float)wv8[k8][l]*x1s[i][c*64 + k8*8 + l];
      acc2[i] += a;
    }
    __syncthreads();
  }
  for (int i = 0; i < 32; ++i) xo[i][j] = (f16)fmaxf(acc2[i], 0.f);
  __syncthreads();
  for (int e = tid; e < 32*256; e += 256){
    int i = e >> 8, jj = e & 255;
    cellin[((size_t)t*32 + i)*800 + jj] = xo[i][jj];
  }
}

// ---------------------------------------------------------------------------
__global__ __launch_bounds__(256) void k_durfill(const float* __restrict__ dur, f16* __restrict__ cellin){
  const int t = blockIdx.x, tid = threadIdx.x;
  for (int e = tid; e < 32*544; e += 256){
    int b = e / 544, c = e - b*544;
    cellin[((size_t)t*32 + b)*800 + 256 + c] = (f16)dur[(size_t)b*417792 + (size_t)t*544 + c];
  }
}

// ---------------------------------------------------------------------------
__global__ __launch_bounds__(256) void k_ws_report(float* __restrict__ out, int n, float val){
  int i = blockIdx.x*256 + threadIdx.x;
  if (i < n) out[i] = val;
}

// ---------------------------------------------------------------------------
// Batch-owner recurrence, per-consumer-lane tags, 8-wave k-split GEMMs.
// L1: all 8 waves do the h-GEMM (part = k-half, 1 serial RTT); x-filler for
// t+1 runs AFTER the z-publish / owner phase (slack), double-buffered zredX.
// L2: early phase A = h2(t-1)@wh2 8-wave (off critical path; h2 published
// half a step earlier), phase B = h1(t)@wx2 8-wave k-split (critical, 1 RTT).
// combine sums the partial-tile arrays. Sync fabric identical to round 8.
// ---------------------------------------------------------------------------
__global__ __launch_bounds__(512, 1) void k_recurrence(
    const f16* __restrict__ cellin, const f16* __restrict__ wxT1,
    const f16* __restrict__ whT1, const f16* __restrict__ w2T,
    f16* __restrict__ H2all, f16* __restrict__ h1buf, f16* __restrict__ h2buf,
    float* __restrict__ zbuf1, float* __restrict__ zbuf2,
    unsigned* __restrict__ tags,
    const float* __restrict__ b1v,
    const float* __restrict__ g1, const float* __restrict__ bn1,
    const float* __restrict__ gc1v, const float* __restrict__ bc1v,
    const float* __restrict__ b2v,
    const float* __restrict__ g2, const float* __restrict__ bn2,
    const float* __restrict__ gc2v, const float* __restrict__ bc2v)
{
  const int tid = threadIdx.x, blk = blockIdx.x;
  const int lane = tid & 63, wv = tid >> 6;
  const int r16 = lane & 15, quad = lane >> 4;
  const int part = wv >> 2, pair = wv & 3, rt = pair >> 1, ct = pair & 1;
  const int g_b = ct*2 + (r16 >> 3), u_b = r16 & 7;   // B-frag col decode
  const int zrow = tid >> 4, zc0 = tid & 15, zc1 = (tid & 15) + 16;
  const int zrt = zrow >> 4, zi = zrow & 15;
  const int arow = rt*16 + r16;

  unsigned* ztag1 = tags;            // 128 x 16 u32 (64B lines)
  unsigned* ztag2 = tags + 2048;     // 128 x 16
  unsigned* htag1 = tags + 4096;     //  32 x 16
  unsigned* htag2 = tags + 4608;     //  32 x 16
  unsigned* ctag  = tags + 5120;     // 128 x 16

  __shared__ f16   swx[3200*8];
  __shared__ float zredA[8][16][17];
  __shared__ float zredX[2][8][16][17];  // L1: x dbuf; L2: [0] = h2 partials
  __shared__ float zs[4096];
  __shared__ float wredS1[8], wredQ1[8], wredS2[8], wredQ2[8];

  if (blk < 128){
    // ======================= LAYER 1 =======================
    const int ub0 = blk*8;
    const int colg = (g_b << 10) + ub0 + u_b;
    f16x8 bfrag[16];
    #pragma unroll
    for (int c2 = 0; c2 < 16; ++c2)
      bfrag[c2] = *(const f16x8*)(whT1 + (size_t)colg*1024 + (part*16 + c2)*32 + quad*8);
    for (int idx = tid; idx < 3200; idx += 512){
      int l = idx & 15, q = (idx >> 4) & 3, v = idx >> 6;
      int c = v % 25, ctx = v / 25;
      int gg = ctx*2 + (l >> 3), uu = l & 7;
      int cg = (gg << 10) + ub0 + uu;
      *(f16x8*)(swx + idx*8) = *(const f16x8*)(wxT1 + (size_t)cg*800 + c*32 + q*8);
    }
    const float zb0 = b1v[((zc0 >> 3) << 10) + ub0 + (zc0 & 7)];
    const float zb1 = b1v[((zc1 >> 3) << 10) + ub0 + (zc1 & 7)];
    const int cbeg = part ? 12 : 0, cend = part ? 25 : 12;  // x-GEMM k ranges
    // owner (batch row = blk) per-unit params, 2 units per thread
    float pgv[4][2], pbv[4][2], gcv[2], bcv[2], cst[2] = {0.f, 0.f};
    if (blk < 32){
      #pragma unroll
      for (int k = 0; k < 2; ++k){
        const int u = 2*tid + k;
        #pragma unroll
        for (int g = 0; g < 4; ++g){
          pgv[g][k] = g1[(g << 10) + u]; pbv[g][k] = bn1[(g << 10) + u];
        }
        gcv[k] = gc1v[u]; bcv[k] = bc1v[u];
      }
    }
    __syncthreads();
    // prologue: x-GEMM for t=0 into zredX slot 0 (8-wave split)
    {
      f32x4 a = {0.f,0.f,0.f,0.f};
      const f16* ap = cellin + (size_t)arow*800 + quad*8;
      for (int c = cbeg; c < cend; ++c){
        f16x8 av = *(const f16x8*)(ap + c*32);
        f16x8 bx = *(const f16x8*)(swx + (size_t)(((ct*25 + c)*4 + quad)*16 + r16)*8);
        a = MFMA_F16(av, bx, a);
      }
      #pragma unroll
      for (int reg = 0; reg < 4; ++reg) zredX[0][wv][quad*4 + reg][r16] = a[reg];
    }
    for (int t = 0; t < 768; ++t){
      // --- h-GEMM: ALL 8 waves, k-split, per-lane h-row tag ---
      if (t > 0){
        tag_wait(htag1 + arow*16, (unsigned)t);
        const f16* hp = h1buf + (size_t)((t-1)&3)*32768 + (size_t)arow*1024 + part*512 + quad*8;
        f32x4 a = gemm16(hp, bfrag);
        #pragma unroll
        for (int reg = 0; reg < 4; ++reg) zredA[wv][quad*4 + reg][r16] = a[reg];
      } else {
        #pragma unroll
        for (int reg = 0; reg < 4; ++reg) zredA[wv][quad*4 + reg][r16] = 0.f;
      }
      __syncthreads();
      // --- combine (h halves + x halves + bias) + z write to zbuf1 ---
      {
        const int xs = t & 1;
        float za  = zredA[zrt*2    ][zi][zc0] + zredA[4 + zrt*2    ][zi][zc0]
                  + zredX[xs][zrt*2    ][zi][zc0] + zredX[xs][4 + zrt*2    ][zi][zc0] + zb0;
        float zbv = zredA[zrt*2 + 1][zi][zc0] + zredA[4 + zrt*2 + 1][zi][zc0]
                  + zredX[xs][zrt*2 + 1][zi][zc0] + zredX[xs][4 + zrt*2 + 1][zi][zc0] + zb1;
        float* zp = zbuf1 + (size_t)zrow*4096;
        st_wt_f32(zp + ((zc0 >> 3) << 10) + ub0 + (zc0 & 7), za);
        st_wt_f32(zp + ((zc1 >> 3) << 10) + ub0 + (zc1 & 7), zbv);
      }
      vm_drain(); __syncthreads();
      if (tid == 0) st_tag(ztag1 + blk*16, (unsigned)(t+1));
      // --- owner gate phase (blocks 0..31): per-slice z tag + load ---
      if (blk < 32){
        if (t >= 4 && tid >= 256 && tid < 384)
          tag_wait(ctag + (tid-256)*16, (unsigned)(t-3));
        tag_wait(ztag1 + (tid & 127)*16, (unsigned)(t+1));
        f32x4 va, vb;
        ld_8f32(zbuf1 + (size_t)blk*4096 + tid*8, va, vb);
        *(f32x4*)(zs + tid*8)     = va;
        *(f32x4*)(zs + tid*8 + 4) = vb;
        float s = va.x+va.y+va.z+va.w + vb.x+vb.y+vb.z+vb.w;
        float q = va.x*va.x+va.y*va.y+va.z*va.z+va.w*va.w
                + vb.x*vb.x+vb.y*vb.y+vb.z*vb.z+vb.w*vb.w;
        s += __shfl_down(s, 32); q += __shfl_down(q, 32);
        s += __shfl_down(s, 16); q += __shfl_down(q, 16);
        s += __shfl_down(s, 8);  q += __shfl_down(q, 8);
        s += __shfl_down(s, 4);  q += __shfl_down(q, 4);
        s += __shfl_down(s, 2);  q += __shfl_down(q, 2);
        s += __shfl_down(s, 1);  q += __shfl_down(q, 1);
        if (lane == 0){ wredS1[wv] = s; wredQ1[wv] = q; }
        __syncthreads();
        float S = 0.f, Q = 0.f;
        #pragma unroll
        for (int w = 0; w < 8; ++w){ S += wredS1[w]; Q += wredQ1[w]; }
        const float m1 = S * (1.f/4096.f);
        const float rs1 = rsqrtf(Q*(1.f/4096.f) - m1*m1 + 1e-5f);
        float oo[2];
        #pragma unroll
        for (int k = 0; k < 2; ++k){
          const int u = 2*tid + k;
          const float ziv = (zs[u]        - m1)*rs1*pgv[0][k] + pbv[0][k];
          const float zf  = (zs[1024 + u] - m1)*rs1*pgv[1][k] + pbv[1][k];
          const float zg  = (zs[2048 + u] - m1)*rs1*pgv[2][k] + pbv[2][k];
          const float zo  = (zs[3072 + u] - m1)*rs1*pgv[3][k] + pbv[3][k];
          cst[k] = sigf(zf)*cst[k] + sigf(ziv)*tanhfast(zg);
          oo[k] = sigf(zo);
        }
        float s2 = cst[0] + cst[1], q2 = cst[0]*cst[0] + cst[1]*cst[1];
        s2 += __shfl_down(s2, 32); q2 += __shfl_down(q2, 32);
        s2 += __shfl_down(s2, 16); q2 += __shfl_down(q2, 16);
        s2 += __shfl_down(s2, 8);  q2 += __shfl_down(q2, 8);
        s2 += __shfl_down(s2, 4);  q2 += __shfl_down(q2, 4);
        s2 += __shfl_down(s2, 2);  q2 += __shfl_down(q2, 2);
        s2 += __shfl_down(s2, 1);  q2 += __shfl_down(q2, 1);
        if (lane == 0){ wredS2[wv] = s2; wredQ2[wv] = q2; }
        __syncthreads();
        float S2 = 0.f, Q2 = 0.f;
        #pragma unroll
        for (int w = 0; w < 8; ++w){ S2 += wredS2[w]; Q2 += wredQ2[w]; }
        const float m2 = S2 * (1.f/1024.f);
        const float rs2 = rsqrtf(Q2*(1.f/1024.f) - m2*m2 + 1e-5f);
        union { f16 f[2]; unsigned u32v; } pk;
        #pragma unroll
        for (int k = 0; k < 2; ++k){
          float arg = fmaf(fmaf(cst[k], rs2, -m2*rs2), gcv[k], bcv[k]);
          float e = exp2f(arg * LOG2E2);
          pk.f[k] = (f16)(oo[k] * fmaf(-2.f, __builtin_amdgcn_rcpf(e + 1.f), 1.f));
        }
        st_wt_u32(h1buf + (size_t)(t&3)*32768 + blk*1024 + 2*tid, pk.u32v);
        vm_drain(); __syncthreads();
        if (tid == 0) st_tag(htag1 + blk*16, (unsigned)(t+1));
      }
      // --- x-filler for t+1 (all 8 waves; off critical path: runs in the
      //     post-publish slack; result consumed after next step's barrier) ---
      if (t < 767){
        f32x4 a = {0.f,0.f,0.f,0.f};
        const f16* ap = cellin + (size_t)(t+1)*25600 + (size_t)arow*800 + quad*8;
        for (int c = cbeg; c < cend; ++c){
          f16x8 av = *(const f16x8*)(ap + c*32);
          f16x8 bx = *(const f16x8*)(swx + (size_t)(((ct*25 + c)*4 + quad)*16 + r16)*8);
          a = MFMA_F16(av, bx, a);
        }
        #pragma unroll
        for (int reg = 0; reg < 4; ++reg) zredX[(t+1)&1][wv][quad*4 + reg][r16] = a[reg];
      }
    }
  } else {
    // ======================= LAYER 2 =======================
    const int blk2 = blk - 128, ub0 = blk2*8;
    const int colg = (g_b << 10) + ub0 + u_b;
    f16x8 bfragH[16], bfragX[16];
    #pragma unroll
    for (int c2 = 0; c2 < 16; ++c2){
      bfragH[c2] = *(const f16x8*)(w2T + (size_t)colg*2048 + 1024 + (part*16 + c2)*32 + quad*8);
      bfragX[c2] = *(const f16x8*)(w2T + (size_t)colg*2048 +        (part*16 + c2)*32 + quad*8);
    }
    const float zb0 = b2v[((zc0 >> 3) << 10) + ub0 + (zc0 & 7)];
    const float zb1 = b2v[((zc1 >> 3) << 10) + ub0 + (zc1 & 7)];
    float pgv[4][2], pbv[4][2], gcv[2], bcv[2], cst[2] = {0.f, 0.f};
    if (blk2 < 32){
      #pragma unroll
      for (int k = 0; k < 2; ++k){
        const int u = 2*tid + k;
        #pragma unroll
        for (int g = 0; g < 4; ++g){
          pgv[g][k] = g2[(g << 10) + u]; pbv[g][k] = bn2[(g << 10) + u];
        }
        gcv[k] = gc2v[u]; bcv[k] = bc2v[u];
      }
    }
    __syncthreads();
    for (int t = 0; t < 768; ++t){
      // --- phase A (early, off critical path): h2(t-1)@wh2, 8-wave k-split ---
      if (t > 0){
        tag_wait(htag2 + arow*16, (unsigned)t);
        const f16* hp = h2buf + (size_t)((t+1)&1)*32768 + (size_t)arow*1024 + part*512 + quad*8;
        f32x4 a = gemm16(hp, bfragH);
        #pragma unroll
        for (int reg = 0; reg < 4; ++reg) zredX[0][wv][quad*4 + reg][r16] = a[reg];
      } else {
        #pragma unroll
        for (int reg = 0; reg < 4; ++reg) zredX[0][wv][quad*4 + reg][r16] = 0.f;
      }
      // --- phase B (critical): h1(t)@wx2, 8-wave k-split ---
      {
        tag_wait(htag1 + arow*16, (unsigned)(t+1));
        const f16* hp = h1buf + (size_t)(t&3)*32768 + (size_t)arow*1024 + part*512 + quad*8;
        f32x4 a = gemm16(hp, bfragX);
        #pragma unroll
        for (int reg = 0; reg < 4; ++reg) zredA[wv][quad*4 + reg][r16] = a[reg];
      }
      __syncthreads();
      if (tid == 0) st_tag(ctag + blk2*16, (unsigned)(t+1));   // h1(t) consumed
      // --- combine (h1 halves + h2 halves + bias) + z2 write to zbuf2 ---
      {
        float za  = zredA[zrt*2    ][zi][zc0] + zredA[4 + zrt*2    ][zi][zc0]
                  + zredX[0][zrt*2    ][zi][zc0] + zredX[0][4 + zrt*2    ][zi][zc0] + zb0;
        float zbv = zredA[zrt*2 + 1][zi][zc0] + zredA[4 + zrt*2 + 1][zi][zc0]
                  + zredX[0][zrt*2 + 1][zi][zc0] + zredX[0][4 + zrt*2 + 1][zi][zc0] + zb1;
        float* zp = zbuf2 + (size_t)zrow*4096;
        st_wt_f32(zp + ((zc0 >> 3) << 10) + ub0 + (zc0 & 7), za);
        st_wt_f32(zp + ((zc1 >> 3) << 10) + ub0 + (zc1 & 7), zbv);
      }
      vm_drain(); __syncthreads();
      if (tid == 0) st_tag(ztag2 + blk2*16, (unsigned)(t+1));
      // --- owner gate phase (blocks 128..159): per-slice z tag + load ---
      if (blk2 < 32){
        tag_wait(ztag2 + (tid & 127)*16, (unsigned)(t+1));
        f32x4 va, vb;
        ld_8f32(zbuf2 + (size_t)blk2*4096 + tid*8, va, vb);
        *(f32x4*)(zs + tid*8)     = va;
        *(f32x4*)(zs + tid*8 + 4) = vb;
        float s = va.x+va.y+va.z+va.w + vb.x+vb.y+vb.z+vb.w;
        float q = va.x*va.x+va.y*va.y+va.z*va.z+va.w*va.w
                + vb.x*vb.x+vb.y*vb.y+vb.z*vb.z+vb.w*vb.w;
        s += __shfl_down(s, 32); q += __shfl_down(q, 32);
        s += __shfl_down(s, 16); q += __shfl_down(q, 16);
        s += __shfl_down(s, 8);  q += __shfl_down(q, 8);
        s += __shfl_down(s, 4);  q += __shfl_down(q, 4);
        s += __shfl_down(s, 2);  q += __shfl_down(q, 2);
        s += __shfl_down(s, 1);  q += __shfl_down(q, 1);
        if (lane == 0){ wredS1[wv] = s; wredQ1[wv] = q; }
        __syncthreads();
        float S = 0.f, Q = 0.f;
        #pragma unroll
        for (int w = 0; w < 8; ++w){ S += wredS1[w]; Q += wredQ1[w]; }
        const float m1 = S * (1.f/4096.f);
        const float rs1 = rsqrtf(Q*(1.f/4096.f) - m1*m1 + 1e-5f);
        float oo[2];
        #pragma unroll
        for (int k = 0; k < 2; ++k){
          const int u = 2*tid + k;
          const float ziv = (zs[u]        - m1)*rs1*pgv[0][k] + pbv[0][k];
          const float zf  = (zs[1024 + u] - m1)*rs1*pgv[1][k] + pbv[1][k];
          const float zg  = (zs[2048 + u] - m1)*rs1*pgv[2][k] + pbv[2][k];
          const float zo  = (zs[3072 + u] - m1)*rs1*pgv[3][k] + pbv[3][k];
          cst[k] = sigf(zf)*cst[k] + sigf(ziv)*tanhfast(zg);
          oo[k] = sigf(zo);
        }
        float s2 = cst[0] + cst[1], q2 = cst[0]*cst[0] + cst[1]*cst[1];
        s2 += __shfl_down(s2, 32); q2 += __shfl_down(q2, 32);
        s2 += __shfl_down(s2, 16); q2 += __shfl_down(q2, 16);
        s2 += __shfl_down(s2, 8);  q2 += __shfl_down(q2, 8);
        s2 += __shfl_down(s2, 4);  q2 += __shfl_down(q2, 4);
        s2 += __shfl_down(s2, 2);  q2 += __shfl_down(q2, 2);
        s2 += __shfl_down(s2, 1);  q2 += __shfl_down(q2, 1);
        if (lane == 0){ wredS2[wv] = s2; wredQ2[wv] = q2; }
        __syncthreads();
        float S2 = 0.f, Q2 = 0.f;
        #pragma unroll
        for (int w = 0; w < 8; ++w){ S2 += wredS2[w]; Q2 += wredQ2[w]; }
        const float m2 = S2 * (1.f/1024.f);
        const float rs2 = rsqrtf(Q2*(1.f/1024.f) - m2*m2 + 1e-5f);
        union { f16 f[2]; unsigned u32v; } pk;
        #pragma unroll
        for (int k = 0; k < 2; ++k){
          float arg = fmaf(fmaf(cst[k], rs2, -m2*rs2), gcv[k], bcv[k]);
          float e = exp2f(arg * LOG2E2);
          pk.f[k] = (f16)(oo[k] * fmaf(-2.f, __builtin_amdgcn_rcpf(e + 1.f), 1.f));
        }
        st_wt_u32(h2buf + (size_t)(t&1)*32768 + blk2*1024 + 2*tid, pk.u32v);
        st_wt_u32(H2all + (size_t)(t+1)*32768 + blk2*1024 + 2*tid, pk.u32v);
        vm_drain(); __syncthreads();
        if (tid == 0) st_tag(htag2 + blk2*16, (unsigned)(t+1));
      }
    }
  }
}

// ---------------------------------------------------------------------------
__global__ __launch_bounds__(256) void k_proj(const f16* __restrict__ H2all, const f16* __restrict__ cellin,
    const f16* __restrict__ projT, const float* __restrict__ projb, float* __restrict__ out){
  const int t = blockIdx.x, tid = threadIdx.x;
  const int lane = tid & 63, wv = tid >> 6;
  const int r16 = lane & 15, quad = lane >> 4;
  __shared__ float pred[4][32][84];
  f32x4 acc[2][5] = {};
  const f16* H2 = H2all + (size_t)(t+1)*32768;
  const f16* CI = cellin + (size_t)t*32*800;
  const int kbeg = wv*13;
  const int kend = (wv == 3) ? 49 : (kbeg + 13);
  for (int ks = kbeg; ks < kend; ++ks){
    const int k0 = ks*32 + quad*8;
    f16x8 a0, a1;
    if (ks < 32){
      a0 = *(const f16x8*)(H2 + r16*1024 + k0);
      a1 = *(const f16x8*)(H2 + (16+r16)*1024 + k0);
    } else {
      a0 = *(const f16x8*)(CI + r16*800 + 256 + (k0 - 1024));
      a1 = *(const f16x8*)(CI + (16+r16)*800 + 256 + (k0 - 1024));
    }
    f16x8 bf[5];
    #pragma unroll
    for (int nt = 0; nt < 5; ++nt)
      bf[nt] = *(const f16x8*)(projT + (size_t)(nt*16 + r16)*1568 + k0);
    #pragma unroll
    for (int nt = 0; nt < 5; ++nt){
      acc[0][nt] = MFMA_F16(a0, bf[nt], acc[0][nt]);
      acc[1][nt] = MFMA_F16(a1, bf[nt], acc[1][nt]);
    }
  }
  #pragma unroll
  for (int mt = 0; mt < 2; ++mt)
    #pragma unroll
    for (int nt = 0; nt < 5; ++nt)
      #pragma unroll
      for (int reg = 0; reg < 4; ++reg)
        pred[wv][mt*16 + quad*4 + reg][nt*16 + r16] = acc[mt][nt][reg];
  __syncthreads();
  for (int e = tid; e < 2560; e += 256){
    int m = e >> 5, b = e & 31;
    float v = pred[0][b][m] + pred[1][b][m] + pred[2][b][m] + pred[3][b][m] + projb[m];
    out[(size_t)b*61440 + (size_t)m*768 + t] = v;
  }
}

// ---------------------------------------------------------------------------
extern "C" void kernel_launch(void* const* d_in, const int* in_sizes, int n_in,
                              void* d_out, int out_size, void* d_ws, size_t ws_size,
                              hipStream_t stream)
{
  const float* duration = (const float*)d_in[0];
  const float* decoder  = (const float*)d_in[1];
  const float* pre_w1   = (const float*)d_in[3];
  const float* pre_w2   = (const float*)d_in[4];
  const float* rnn1_wx  = (const float*)d_in[5];
  const float* rnn1_wh  = (const float*)d_in[6];
  const float* rnn1_b   = (const float*)d_in[7];
  const float* rnn1_g   = (const float*)d_in[8];
  const float* rnn1_bn  = (const float*)d_in[9];
  const float* rnn1_gc  = (const float*)d_in[10];
  const float* rnn1_bc  = (const float*)d_in[11];
  const float* rnn2_wx  = (const float*)d_in[12];
  const float* rnn2_wh  = (const float*)d_in[13];
  const float* rnn2_b   = (const float*)d_in[14];
  const float* rnn2_g   = (const float*)d_in[15];
  const float* rnn2_bn  = (const float*)d_in[16];
  const float* rnn2_gc  = (const float*)d_in[17];
  const float* rnn2_bc  = (const float*)d_in[18];
  const float* proj_w   = (const float*)d_in[19];
  const float* proj_b   = (const float*)d_in[20];
  float* out = (float*)d_out;

  char* w = (char*)d_ws;
  f16* cellin = (f16*)w;      w += (size_t)24576*800*2;
  f16* wxT1   = (f16*)w;      w += (size_t)4096*800*2;
  f16* whT1   = (f16*)w;      w += (size_t)4096*1024*2;
  f16* w2T    = (f16*)w;      w += (size_t)4096*2048*2;
  f16* projT  = (f16*)w;      w += 262144;
  f16* H2all  = (f16*)w;      w += (size_t)769*32768*2;
  f16* h1buf  = (f16*)w;      w += 262144;   // 4 slots x 32x1024 f16
  f16* h2buf  = (f16*)w;      w += 131072;   // 2 slots
  float* zbuf1 = (float*)w;   w += (size_t)32*4096*4;
  float* zbuf2 = (float*)w;   w += (size_t)32*4096*4;
  unsigned* tags = (unsigned*)w; w += 28672;
  const size_t need = (size_t)((char*)w - (char*)d_ws);
  if (ws_size < need){
    k_ws_report<<<(out_size + 255)/256, 256, 0, stream>>>(out, out_size, (float)(ws_size >> 20));
    return;
  }

  (void)hipMemsetAsync(tags, 0, 28672, stream);
  (void)hipMemsetAsync(h1buf, 0, 262144, stream);
  (void)hipMemsetAsync(h2buf, 0, 131072, stream);

  k_transpose_f16<<<dim3(4096/32, 25), 256, 0, stream>>>(rnn1_wx, wxT1, 800, 4096, 800, 0);
  k_transpose_f16<<<dim3(4096/32, 32), 256, 0, stream>>>(rnn1_wh, whT1, 1024, 4096, 1024, 0);
  k_transpose_f16<<<dim3(4096/32, 32), 256, 0, stream>>>(rnn2_wx, w2T, 1024, 4096, 2048, 0);
  k_transpose_f16<<<dim3(4096/32, 32), 256, 0, stream>>>(rnn2_wh, w2T, 1024, 4096, 2048, 1024);
  k_transpose_f16<<<dim3(3, 49), 256, 0, stream>>>(proj_w, projT, 1568, 80, 1568, 0);
  k_prenet<<<768, 256, 0, stream>>>(decoder, pre_w1, pre_w2, cellin);
  k_durfill<<<768, 256, 0, stream>>>(duration, cellin);
  k_recurrence<<<256, 512, 0, stream>>>(cellin, wxT1, whT1, w2T, H2all, h1buf, h2buf,
      zbuf1, zbuf2, tags,
      rnn1_b, rnn1_g, rnn1_bn, rnn1_gc, rnn1_bc,
      rnn2_b, rnn2_g, rnn2_bn, rnn2_gc, rnn2_bc);
  k_proj<<<768, 256, 0, stream>>>(H2all, cellin, projT, proj_b, out);
}

// Round 10
// 9685.527 us; speedup vs baseline: 1.0854x; 1.0854x over previous
//
#include <hip/hip_runtime.h>
#include <cstdint>
#include <cstddef>

typedef _Float16 f16;
typedef _Float16 f16x8 __attribute__((ext_vector_type(8)));
typedef float f32x4 __attribute__((ext_vector_type(4)));

#define MFMA_F16(a,b,c) __builtin_amdgcn_mfma_f32_16x16x32_f16((a),(b),(c),0,0,0)

#define LOG2E  1.4426950408889634f
#define LOG2E2 2.885390081777927f

// fast sigmoid/tanh via exp2 + rcp (same numeric family as the proven h path)
__device__ __forceinline__ float sigf(float x){
  return __builtin_amdgcn_rcpf(1.f + exp2f(-x * LOG2E));
}
__device__ __forceinline__ float tanhfast(float x){
  float e = exp2f(x * LOG2E2);
  return fmaf(-2.f, __builtin_amdgcn_rcpf(e + 1.f), 1.f);
}

__device__ __forceinline__ void st_wt_f32(float* p, float v){
  asm volatile("global_store_dword %0, %1, off sc0 sc1" :: "v"(p), "v"(v) : "memory");
}
__device__ __forceinline__ void st_wt_u32(f16* p, unsigned v){
  asm volatile("global_store_dword %0, %1, off sc0 sc1" :: "v"(p), "v"(v) : "memory");
}
__device__ __forceinline__ void st_tag(unsigned* p, unsigned v){
  asm volatile("global_store_dword %0, %1, off sc0 sc1" :: "v"(p), "v"(v) : "memory");
}
__device__ __forceinline__ void tag_wait(const unsigned* p, unsigned target){
  for (;;){
    unsigned v;
    asm volatile("global_load_dword %0, %1, off sc0 sc1\n\ts_waitcnt vmcnt(0)"
                 : "=v"(v) : "v"(p) : "memory");
    if (v >= target) return;
    __builtin_amdgcn_s_sleep(1);
  }
}
__device__ __forceinline__ void vm_drain(){ asm volatile("s_waitcnt vmcnt(0)" ::: "memory"); }

template<int N> __device__ __forceinline__ void vm_waitN(){
  asm volatile("s_waitcnt vmcnt(%0)" :: "i"(N) : "memory");
  __builtin_amdgcn_sched_barrier(0);
}

// Coherent read of 8 consecutive f32 (one 32B slice of a z row).
__device__ __forceinline__ void ld_8f32(const float* p, f32x4& a, f32x4& b){
  asm volatile(
    "global_load_dwordx4 %0, %2, off sc0 sc1\n\t"
    "global_load_dwordx4 %1, %2, off offset:16 sc0 sc1\n\t"
    "s_waitcnt vmcnt(0)"
    : "=&v"(a), "=&v"(b) : "v"(p) : "memory");
}

// Coherent batched ISSUE (no wait) of 8 consecutive 64B k-chunks of one row.
__device__ __forceinline__ void ld8_issue(const f16* p, f16x8* f){
  asm volatile(
    "global_load_dwordx4 %0, %8, off sc0 sc1\n\t"
    "global_load_dwordx4 %1, %8, off offset:64 sc0 sc1\n\t"
    "global_load_dwordx4 %2, %8, off offset:128 sc0 sc1\n\t"
    "global_load_dwordx4 %3, %8, off offset:192 sc0 sc1\n\t"
    "global_load_dwordx4 %4, %8, off offset:256 sc0 sc1\n\t"
    "global_load_dwordx4 %5, %8, off offset:320 sc0 sc1\n\t"
    "global_load_dwordx4 %6, %8, off offset:384 sc0 sc1\n\t"
    "global_load_dwordx4 %7, %8, off offset:448 sc0 sc1"
    : "=&v"(f[0]),"=&v"(f[1]),"=&v"(f[2]),"=&v"(f[3]),
      "=&v"(f[4]),"=&v"(f[5]),"=&v"(f[6]),"=&v"(f[7])
    : "v"(p) : "memory");
}

// 32-row x 32-col x K=1024 GEMM slice. A rows from coherent global, 2 batches
// of 8 loads in flight (counted vmcnt waits); B frags in registers.
__device__ __forceinline__ f32x4 gemm32r(const f16* hp, const f16x8* bfrag){
  f32x4 a = {0.f,0.f,0.f,0.f};
  f16x8 fA[8], fB[8];
  ld8_issue(hp,       fA);
  ld8_issue(hp + 256, fB);
  vm_waitN<8>();
  #pragma unroll
  for (int kk = 0; kk < 8; ++kk) a = MFMA_F16(fA[kk], bfrag[kk], a);
  ld8_issue(hp + 512, fA);
  vm_waitN<8>();
  #pragma unroll
  for (int kk = 0; kk < 8; ++kk) a = MFMA_F16(fB[kk], bfrag[8 + kk], a);
  ld8_issue(hp + 768, fB);
  vm_waitN<8>();
  #pragma unroll
  for (int kk = 0; kk < 8; ++kk) a = MFMA_F16(fA[kk], bfrag[16 + kk], a);
  vm_waitN<0>();
  #pragma unroll
  for (int kk = 0; kk < 8; ++kk) a = MFMA_F16(fB[kk], bfrag[24 + kk], a);
  return a;
}

// ---------------------------------------------------------------------------
__global__ __launch_bounds__(256) void k_transpose_f16(const float* __restrict__ src,
    f16* __restrict__ dst, int K, int N, int dstStride, int dstOff){
  const int n0 = blockIdx.x*32, k0 = blockIdx.y*32, tid = threadIdx.x;
  __shared__ float tl[32][33];
  #pragma unroll
  for (int rep = 0; rep < 4; ++rep){
    int e = rep*256 + tid; int i = e >> 5, j = e & 31;
    int k = k0 + i, n = n0 + j;
    tl[i][j] = (k < K && n < N) ? src[(size_t)k*N + n] : 0.f;
  }
  __syncthreads();
  #pragma unroll
  for (int rep = 0; rep < 4; ++rep){
    int e = rep*256 + tid; int i2 = e & 31, j2 = e >> 5;
    int n = n0 + j2, k = k0 + i2;
    if (k < K && n < N) dst[(size_t)n*dstStride + dstOff + k] = (f16)tl[i2][j2];
  }
}

// ---------------------------------------------------------------------------
__global__ __launch_bounds__(256) void k_prenet(const float* __restrict__ dec,
    const float* __restrict__ w1, const float* __restrict__ w2, f16* __restrict__ cellin){
  const int t = blockIdx.x, tid = threadIdx.x;
  __shared__ float sin_[32][81];
  __shared__ f16   w1T[256][88];
  __shared__ float x1s[32][260];
  __shared__ f16   w2c[256][72];
  __shared__ f16   xo[32][256];
  for (int e = tid; e < 32*80; e += 256){
    int i = e/80, m = e - i*80;
    sin_[i][m] = (t == 0) ? 0.f : dec[(size_t)i*61440 + (size_t)m*768 + (t-1)];
  }
  for (int e = tid; e < 80*256; e += 256){ int m = e >> 8, j = e & 255; w1T[j][m] = (f16)w1[e]; }
  __syncthreads();
  const int j = tid;
  for (int i = 0; i < 32; ++i){
    float a = 0.f;
    #pragma unroll
    for (int m8 = 0; m8 < 10; ++m8){
      f16x8 wvv = *(const f16x8*)&w1T[j][m8*8];
      #pragma unroll
      for (int l = 0; l < 8; ++l) a += (float)wvv[l] * sin_[i][m8*8 + l];
    }
    x1s[i][j] = fmaxf(a, 0.f);
  }
  __syncthreads();
  float acc2[32];
  #pragma unroll
  for (int i = 0; i < 32; ++i) acc2[i] = 0.f;
  for (int c = 0; c < 4; ++c){
    for (int e = tid; e < 64*256; e += 256){
      int kl = e >> 8, jj = e & 255;
      w2c[jj][kl] = (f16)w2[(size_t)(c*64 + kl)*256 + jj];
    }
    __syncthreads();
    f16x8 wv8[8];
    #pragma unroll
    for (int k8 = 0; k8 < 8; ++k8) wv8[k8] = *(const f16x8*)&w2c[j][k8*8];
    for (int i = 0; i < 32; ++i){
      float a = 0.f;
      #pragma unroll
      for (int k8 = 0; k8 < 8; ++k8)
        #pragma unroll
        for (int l = 0; l < 8; ++l) a += (float)wv8[k8][l]*x1s[i][c*64 + k8*8 + l];
      acc2[i] += a;
    }
    __syncthreads();
  }
  for (int i = 0; i < 32; ++i) xo[i][j] = (f16)fmaxf(acc2[i], 0.f);
  __syncthreads();
  for (int e = tid; e < 32*256; e += 256){
    int i = e >> 8, jj = e & 255;
    cellin[((size_t)t*32 + i)*800 + jj] = xo[i][jj];
  }
}

// ---------------------------------------------------------------------------
__global__ __launch_bounds__(256) void k_durfill(const float* __restrict__ dur, f16* __restrict__ cellin){
  const int t = blockIdx.x, tid = threadIdx.x;
  for (int e = tid; e < 32*544; e += 256){
    int b = e / 544, c = e - b*544;
    cellin[((size_t)t*32 + b)*800 + 256 + c] = (f16)dur[(size_t)b*417792 + (size_t)t*544 + c];
  }
}

// ---------------------------------------------------------------------------
__global__ __launch_bounds__(256) void k_ws_report(float* __restrict__ out, int n, float val){
  int i = blockIdx.x*256 + threadIdx.x;
  if (i < n) out[i] = val;
}

// ---------------------------------------------------------------------------
// Batch-owner recurrence with PER-CONSUMER-LANE tag gating (round-8 best).
// Every consumer touches exactly one producer's line:
//   GEMM lane (A-row arow)  <- h row arow  <- owner block arow's tag
//   owner thread tid (z slice tid*8..+8) <- GEMM block (tid&127)'s tag
// so each lane tag_waits its own producer then loads immediately; straggler
// detection overlaps with ready-data reads, and the block-wide max moves to
// the existing LDS-reduce barrier. Buffer reuse orderings preserved
// (zbuf(t+1) writes are behind owner's z(t) read via htag(t) -> GEMM(t+1)).
// R9's 8-wave k-split GEMM REGRESSED (doubled tag fan-in + LDS combine
// traffic; gemm32r already has ~1 serial RTT) — do not reapply.
// ---------------------------------------------------------------------------
__global__ __launch_bounds__(512, 1) void k_recurrence(
    const f16* __restrict__ cellin, const f16* __restrict__ wxT1,
    const f16* __restrict__ whT1, const f16* __restrict__ w2T,
    f16* __restrict__ H2all, f16* __restrict__ h1buf, f16* __restrict__ h2buf,
    float* __restrict__ zbuf1, float* __restrict__ zbuf2,
    unsigned* __restrict__ tags,
    const float* __restrict__ b1v,
    const float* __restrict__ g1, const float* __restrict__ bn1,
    const float* __restrict__ gc1v, const float* __restrict__ bc1v,
    const float* __restrict__ b2v,
    const float* __restrict__ g2, const float* __restrict__ bn2,
    const float* __restrict__ gc2v, const float* __restrict__ bc2v)
{
  const int tid = threadIdx.x, blk = blockIdx.x;
  const int lane = tid & 63, wv = tid >> 6;
  const int r16 = lane & 15, quad = lane >> 4;
  const int part = wv >> 2, pair = wv & 3, rt = pair >> 1, ct = pair & 1;
  const int g_b = ct*2 + (r16 >> 3), u_b = r16 & 7;   // B-frag col decode
  const int zrow = tid >> 4, zc0 = tid & 15, zc1 = (tid & 15) + 16;
  const int zrt = zrow >> 4, zi = zrow & 15;
  const int arow = rt*16 + r16;

  unsigned* ztag1 = tags;            // 128 x 16 u32 (64B lines)
  unsigned* ztag2 = tags + 2048;     // 128 x 16
  unsigned* htag1 = tags + 4096;     //  32 x 16
  unsigned* htag2 = tags + 4608;     //  32 x 16
  unsigned* ctag  = tags + 5120;     // 128 x 16

  __shared__ f16   swx[3200*8];
  __shared__ float zredA[8][16][17];
  __shared__ float zredX[2][4][16][17];
  __shared__ float zs[4096];
  __shared__ float wredS1[8], wredQ1[8], wredS2[8], wredQ2[8];

  f16x8 bfrag[32];

  if (blk < 128){
    // ======================= LAYER 1 =======================
    const int ub0 = blk*8;
    const int colg = (g_b << 10) + ub0 + u_b;
    if (part == 0){
      #pragma unroll
      for (int c = 0; c < 32; ++c)
        bfrag[c] = *(const f16x8*)(whT1 + (size_t)colg*1024 + c*32 + quad*8);
    }
    for (int idx = tid; idx < 3200; idx += 512){
      int l = idx & 15, q = (idx >> 4) & 3, v = idx >> 6;
      int c = v % 25, ctx = v / 25;
      int gg = ctx*2 + (l >> 3), uu = l & 7;
      int cg = (gg << 10) + ub0 + uu;
      *(f16x8*)(swx + idx*8) = *(const f16x8*)(wxT1 + (size_t)cg*800 + c*32 + q*8);
    }
    const float zb0 = b1v[((zc0 >> 3) << 10) + ub0 + (zc0 & 7)];
    const float zb1 = b1v[((zc1 >> 3) << 10) + ub0 + (zc1 & 7)];
    // owner (batch row = blk) per-unit params, 2 units per thread
    float pgv[4][2], pbv[4][2], gcv[2], bcv[2], cst[2] = {0.f, 0.f};
    if (blk < 32){
      #pragma unroll
      for (int k = 0; k < 2; ++k){
        const int u = 2*tid + k;
        #pragma unroll
        for (int g = 0; g < 4; ++g){
          pgv[g][k] = g1[(g << 10) + u]; pbv[g][k] = bn1[(g << 10) + u];
        }
        gcv[k] = gc1v[u]; bcv[k] = bc1v[u];
      }
    }
    __syncthreads();
    // prologue: x-GEMM for t=0 into zredX slot 0
    if (part == 1){
      f32x4 a = {0.f,0.f,0.f,0.f};
      const f16* ap = cellin + (size_t)arow*800 + quad*8;
      for (int c = 0; c < 25; ++c){
        f16x8 av = *(const f16x8*)(ap + c*32);
        f16x8 bx = *(const f16x8*)(swx + (size_t)(((ct*25 + c)*4 + quad)*16 + r16)*8);
        a = MFMA_F16(av, bx, a);
      }
      #pragma unroll
      for (int reg = 0; reg < 4; ++reg) zredX[0][wv-4][quad*4 + reg][r16] = a[reg];
    }
    for (int t = 0; t < 768; ++t){
      // --- GEMM phase: part0 h-GEMM (per-lane h-row tag) || part1 x-filler ---
      if (part == 0){
        if (t > 0){
          tag_wait(htag1 + arow*16, (unsigned)t);
          const f16* hp = h1buf + (size_t)((t-1)&3)*32768 + (size_t)arow*1024 + quad*8;
          f32x4 a = gemm32r(hp, bfrag);
          #pragma unroll
          for (int reg = 0; reg < 4; ++reg) zredA[wv][quad*4 + reg][r16] = a[reg];
        } else {
          #pragma unroll
          for (int reg = 0; reg < 4; ++reg) zredA[wv][quad*4 + reg][r16] = 0.f;
        }
      } else if (t < 767){
        f32x4 a = {0.f,0.f,0.f,0.f};
        const f16* ap = cellin + (size_t)(t+1)*25600 + (size_t)arow*800 + quad*8;
        for (int c = 0; c < 25; ++c){
          f16x8 av = *(const f16x8*)(ap + c*32);
          f16x8 bx = *(const f16x8*)(swx + (size_t)(((ct*25 + c)*4 + quad)*16 + r16)*8);
          a = MFMA_F16(av, bx, a);
        }
        #pragma unroll
        for (int reg = 0; reg < 4; ++reg) zredX[(t+1)&1][wv-4][quad*4 + reg][r16] = a[reg];
      }
      __syncthreads();
      // --- combine + biased z write to zbuf1 ---
      {
        const int xs = t & 1;
        float za  = zredA[zrt*2    ][zi][zc0] + zredX[xs][zrt*2    ][zi][zc0] + zb0;
        float zbv = zredA[zrt*2 + 1][zi][zc0] + zredX[xs][zrt*2 + 1][zi][zc0] + zb1;
        float* zp = zbuf1 + (size_t)zrow*4096;
        st_wt_f32(zp + ((zc0 >> 3) << 10) + ub0 + (zc0 & 7), za);
        st_wt_f32(zp + ((zc1 >> 3) << 10) + ub0 + (zc1 & 7), zbv);
      }
      vm_drain(); __syncthreads();
      if (tid == 0) st_tag(ztag1 + blk*16, (unsigned)(t+1));
      // --- owner gate phase (blocks 0..31): per-slice z tag + load ---
      if (blk < 32){
        if (t >= 4 && tid >= 256 && tid < 384)
          tag_wait(ctag + (tid-256)*16, (unsigned)(t-3));
        tag_wait(ztag1 + (tid & 127)*16, (unsigned)(t+1));
        f32x4 va, vb;
        ld_8f32(zbuf1 + (size_t)blk*4096 + tid*8, va, vb);
        *(f32x4*)(zs + tid*8)     = va;
        *(f32x4*)(zs + tid*8 + 4) = vb;
        float s = va.x+va.y+va.z+va.w + vb.x+vb.y+vb.z+vb.w;
        float q = va.x*va.x+va.y*va.y+va.z*va.z+va.w*va.w
                + vb.x*vb.x+vb.y*vb.y+vb.z*vb.z+vb.w*vb.w;
        s += __shfl_down(s, 32); q += __shfl_down(q, 32);
        s += __shfl_down(s, 16); q += __shfl_down(q, 16);
        s += __shfl_down(s, 8);  q += __shfl_down(q, 8);
        s += __shfl_down(s, 4);  q += __shfl_down(q, 4);
        s += __shfl_down(s, 2);  q += __shfl_down(q, 2);
        s += __shfl_down(s, 1);  q += __shfl_down(q, 1);
        if (lane == 0){ wredS1[wv] = s; wredQ1[wv] = q; }
        __syncthreads();
        float S = 0.f, Q = 0.f;
        #pragma unroll
        for (int w = 0; w < 8; ++w){ S += wredS1[w]; Q += wredQ1[w]; }
        const float m1 = S * (1.f/4096.f);
        const float rs1 = rsqrtf(Q*(1.f/4096.f) - m1*m1 + 1e-5f);
        float oo[2];
        #pragma unroll
        for (int k = 0; k < 2; ++k){
          const int u = 2*tid + k;
          const float ziv = (zs[u]        - m1)*rs1*pgv[0][k] + pbv[0][k];
          const float zf  = (zs[1024 + u] - m1)*rs1*pgv[1][k] + pbv[1][k];
          const float zg  = (zs[2048 + u] - m1)*rs1*pgv[2][k] + pbv[2][k];
          const float zo  = (zs[3072 + u] - m1)*rs1*pgv[3][k] + pbv[3][k];
          cst[k] = sigf(zf)*cst[k] + sigf(ziv)*tanhfast(zg);
          oo[k] = sigf(zo);
        }
        float s2 = cst[0] + cst[1], q2 = cst[0]*cst[0] + cst[1]*cst[1];
        s2 += __shfl_down(s2, 32); q2 += __shfl_down(q2, 32);
        s2 += __shfl_down(s2, 16); q2 += __shfl_down(q2, 16);
        s2 += __shfl_down(s2, 8);  q2 += __shfl_down(q2, 8);
        s2 += __shfl_down(s2, 4);  q2 += __shfl_down(q2, 4);
        s2 += __shfl_down(s2, 2);  q2 += __shfl_down(q2, 2);
        s2 += __shfl_down(s2, 1);  q2 += __shfl_down(q2, 1);
        if (lane == 0){ wredS2[wv] = s2; wredQ2[wv] = q2; }
        __syncthreads();
        float S2 = 0.f, Q2 = 0.f;
        #pragma unroll
        for (int w = 0; w < 8; ++w){ S2 += wredS2[w]; Q2 += wredQ2[w]; }
        const float m2 = S2 * (1.f/1024.f);
        const float rs2 = rsqrtf(Q2*(1.f/1024.f) - m2*m2 + 1e-5f);
        union { f16 f[2]; unsigned u32v; } pk;
        #pragma unroll
        for (int k = 0; k < 2; ++k){
          float arg = fmaf(fmaf(cst[k], rs2, -m2*rs2), gcv[k], bcv[k]);
          float e = exp2f(arg * LOG2E2);
          pk.f[k] = (f16)(oo[k] * fmaf(-2.f, __builtin_amdgcn_rcpf(e + 1.f), 1.f));
        }
        st_wt_u32(h1buf + (size_t)(t&3)*32768 + blk*1024 + 2*tid, pk.u32v);
        vm_drain(); __syncthreads();
        if (tid == 0) st_tag(htag1 + blk*16, (unsigned)(t+1));
      }
    }
  } else {
    // ======================= LAYER 2 =======================
    const int blk2 = blk - 128, ub0 = blk2*8;
    const int colg = (g_b << 10) + ub0 + u_b;
    {
      const f16* wsrc = w2T + (size_t)colg*2048 + (part == 0 ? 1024 : 0);
      #pragma unroll
      for (int c = 0; c < 32; ++c)
        bfrag[c] = *(const f16x8*)(wsrc + c*32 + quad*8);
    }
    const float zb0 = b2v[((zc0 >> 3) << 10) + ub0 + (zc0 & 7)];
    const float zb1 = b2v[((zc1 >> 3) << 10) + ub0 + (zc1 & 7)];
    float pgv[4][2], pbv[4][2], gcv[2], bcv[2], cst[2] = {0.f, 0.f};
    if (blk2 < 32){
      #pragma unroll
      for (int k = 0; k < 2; ++k){
        const int u = 2*tid + k;
        #pragma unroll
        for (int g = 0; g < 4; ++g){
          pgv[g][k] = g2[(g << 10) + u]; pbv[g][k] = bn2[(g << 10) + u];
        }
        gcv[k] = gc2v[u]; bcv[k] = bc2v[u];
      }
    }
    __syncthreads();
    for (int t = 0; t < 768; ++t){
      // --- GEMM: part0 h2(t-1) row-gated; part1 h1(t) row-gated ---
      if (part == 0){
        if (t > 0){
          tag_wait(htag2 + arow*16, (unsigned)t);
          const f16* hp = h2buf + (size_t)((t+1)&1)*32768 + (size_t)arow*1024 + quad*8;
          f32x4 a = gemm32r(hp, bfrag);
          #pragma unroll
          for (int reg = 0; reg < 4; ++reg) zredA[wv][quad*4 + reg][r16] = a[reg];
        } else {
          #pragma unroll
          for (int reg = 0; reg < 4; ++reg) zredA[wv][quad*4 + reg][r16] = 0.f;
        }
      } else {
        tag_wait(htag1 + arow*16, (unsigned)(t+1));
        const f16* hp = h1buf + (size_t)(t&3)*32768 + (size_t)arow*1024 + quad*8;
        f32x4 a = gemm32r(hp, bfrag);
        #pragma unroll
        for (int reg = 0; reg < 4; ++reg) zredA[wv][quad*4 + reg][r16] = a[reg];
      }
      __syncthreads();
      if (tid == 0) st_tag(ctag + blk2*16, (unsigned)(t+1));   // h1(t) consumed
      // --- combine + biased z2 write to zbuf2 ---
      {
        float za  = zredA[zrt*2    ][zi][zc0] + zredA[4 + zrt*2    ][zi][zc0] + zb0;
        float zbv = zredA[zrt*2 + 1][zi][zc0] + zredA[4 + zrt*2 + 1][zi][zc0] + zb1;
        float* zp = zbuf2 + (size_t)zrow*4096;
        st_wt_f32(zp + ((zc0 >> 3) << 10) + ub0 + (zc0 & 7), za);
        st_wt_f32(zp + ((zc1 >> 3) << 10) + ub0 + (zc1 & 7), zbv);
      }
      vm_drain(); __syncthreads();
      if (tid == 0) st_tag(ztag2 + blk2*16, (unsigned)(t+1));
      // --- owner gate phase (blocks 128..159): per-slice z tag + load ---
      if (blk2 < 32){
        tag_wait(ztag2 + (tid & 127)*16, (unsigned)(t+1));
        f32x4 va, vb;
        ld_8f32(zbuf2 + (size_t)blk2*4096 + tid*8, va, vb);
        *(f32x4*)(zs + tid*8)     = va;
        *(f32x4*)(zs + tid*8 + 4) = vb;
        float s = va.x+va.y+va.z+va.w + vb.x+vb.y+vb.z+vb.w;
        float q = va.x*va.x+va.y*va.y+va.z*va.z+va.w*va.w
                + vb.x*vb.x+vb.y*vb.y+vb.z*vb.z+vb.w*vb.w;
        s += __shfl_down(s, 32); q += __shfl_down(q, 32);
        s += __shfl_down(s, 16); q += __shfl_down(q, 16);
        s += __shfl_down(s, 8);  q += __shfl_down(q, 8);
        s += __shfl_down(s, 4);  q += __shfl_down(q, 4);
        s += __shfl_down(s, 2);  q += __shfl_down(q, 2);
        s += __shfl_down(s, 1);  q += __shfl_down(q, 1);
        if (lane == 0){ wredS1[wv] = s; wredQ1[wv] = q; }
        __syncthreads();
        float S = 0.f, Q = 0.f;
        #pragma unroll
        for (int w = 0; w < 8; ++w){ S += wredS1[w]; Q += wredQ1[w]; }
        const float m1 = S * (1.f/4096.f);
        const float rs1 = rsqrtf(Q*(1.f/4096.f) - m1*m1 + 1e-5f);
        float oo[2];
        #pragma unroll
        for (int k = 0; k < 2; ++k){
          const int u = 2*tid + k;
          const float ziv = (zs[u]        - m1)*rs1*pgv[0][k] + pbv[0][k];
          const float zf  = (zs[1024 + u] - m1)*rs1*pgv[1][k] + pbv[1][k];
          const float zg  = (zs[2048 + u] - m1)*rs1*pgv[2][k] + pbv[2][k];
          const float zo  = (zs[3072 + u] - m1)*rs1*pgv[3][k] + pbv[3][k];
          cst[k] = sigf(zf)*cst[k] + sigf(ziv)*tanhfast(zg);
          oo[k] = sigf(zo);
        }
        float s2 = cst[0] + cst[1], q2 = cst[0]*cst[0] + cst[1]*cst[1];
        s2 += __shfl_down(s2, 32); q2 += __shfl_down(q2, 32);
        s2 += __shfl_down(s2, 16); q2 += __shfl_down(q2, 16);
        s2 += __shfl_down(s2, 8);  q2 += __shfl_down(q2, 8);
        s2 += __shfl_down(s2, 4);  q2 += __shfl_down(q2, 4);
        s2 += __shfl_down(s2, 2);  q2 += __shfl_down(q2, 2);
        s2 += __shfl_down(s2, 1);  q2 += __shfl_down(q2, 1);
        if (lane == 0){ wredS2[wv] = s2; wredQ2[wv] = q2; }
        __syncthreads();
        float S2 = 0.f, Q2 = 0.f;
        #pragma unroll
        for (int w = 0; w < 8; ++w){ S2 += wredS2[w]; Q2 += wredQ2[w]; }
        const float m2 = S2 * (1.f/1024.f);
        const float rs2 = rsqrtf(Q2*(1.f/1024.f) - m2*m2 + 1e-5f);
        union { f16 f[2]; unsigned u32v; } pk;
        #pragma unroll
        for (int k = 0; k < 2; ++k){
          float arg = fmaf(fmaf(cst[k], rs2, -m2*rs2), gcv[k], bcv[k]);
          float e = exp2f(arg * LOG2E2);
          pk.f[k] = (f16)(oo[k] * fmaf(-2.f, __builtin_amdgcn_rcpf(e + 1.f), 1.f));
        }
        st_wt_u32(h2buf + (size_t)(t&1)*32768 + blk2*1024 + 2*tid, pk.u32v);
        st_wt_u32(H2all + (size_t)(t+1)*32768 + blk2*1024 + 2*tid, pk.u32v);
        vm_drain(); __syncthreads();
        if (tid == 0) st_tag(htag2 + blk2*16, (unsigned)(t+1));
      }
    }
  }
}

// ---------------------------------------------------------------------------
__global__ __launch_bounds__(256) void k_proj(const f16* __restrict__ H2all, const f16* __restrict__ cellin,
    const f16* __restrict__ projT, const float* __restrict__ projb, float* __restrict__ out){
  const int t = blockIdx.x, tid = threadIdx.x;
  const int lane = tid & 63, wv = tid >> 6;
  const int r16 = lane & 15, quad = lane >> 4;
  __shared__ float pred[4][32][84];
  f32x4 acc[2][5] = {};
  const f16* H2 = H2all + (size_t)(t+1)*32768;
  const f16* CI = cellin + (size_t)t*32*800;
  const int kbeg = wv*13;
  const int kend = (wv == 3) ? 49 : (kbeg + 13);
  for (int ks = kbeg; ks < kend; ++ks){
    const int k0 = ks*32 + quad*8;
    f16x8 a0, a1;
    if (ks < 32){
      a0 = *(const f16x8*)(H2 + r16*1024 + k0);
      a1 = *(const f16x8*)(H2 + (16+r16)*1024 + k0);
    } else {
      a0 = *(const f16x8*)(CI + r16*800 + 256 + (k0 - 1024));
      a1 = *(const f16x8*)(CI + (16+r16)*800 + 256 + (k0 - 1024));
    }
    f16x8 bf[5];
    #pragma unroll
    for (int nt = 0; nt < 5; ++nt)
      bf[nt] = *(const f16x8*)(projT + (size_t)(nt*16 + r16)*1568 + k0);
    #pragma unroll
    for (int nt = 0; nt < 5; ++nt){
      acc[0][nt] = MFMA_F16(a0, bf[nt], acc[0][nt]);
      acc[1][nt] = MFMA_F16(a1, bf[nt], acc[1][nt]);
    }
  }
  #pragma unroll
  for (int mt = 0; mt < 2; ++mt)
    #pragma unroll
    for (int nt = 0; nt < 5; ++nt)
      #pragma unroll
      for (int reg = 0; reg < 4; ++reg)
        pred[wv][mt*16 + quad*4 + reg][nt*16 + r16] = acc[mt][nt][reg];
  __syncthreads();
  for (int e = tid; e < 2560; e += 256){
    int m = e >> 5, b = e & 31;
    float v = pred[0][b][m] + pred[1][b][m] + pred[2][b][m] + pred[3][b][m] + projb[m];
    out[(size_t)b*61440 + (size_t)m*768 + t] = v;
  }
}

// ---------------------------------------------------------------------------
extern "C" void kernel_launch(void* const* d_in, const int* in_sizes, int n_in,
                              void* d_out, int out_size, void* d_ws, size_t ws_size,
                              hipStream_t stream)
{
  const float* duration = (const float*)d_in[0];
  const float* decoder  = (const float*)d_in[1];
  const float* pre_w1   = (const float*)d_in[3];
  const float* pre_w2   = (const float*)d_in[4];
  const float* rnn1_wx  = (const float*)d_in[5];
  const float* rnn1_wh  = (const float*)d_in[6];
  const float* rnn1_b   = (const float*)d_in[7];
  const float* rnn1_g   = (const float*)d_in[8];
  const float* rnn1_bn  = (const float*)d_in[9];
  const float* rnn1_gc  = (const float*)d_in[10];
  const float* rnn1_bc  = (const float*)d_in[11];
  const float* rnn2_wx  = (const float*)d_in[12];
  const float* rnn2_wh  = (const float*)d_in[13];
  const float* rnn2_b   = (const float*)d_in[14];
  const float* rnn2_g   = (const float*)d_in[15];
  const float* rnn2_bn  = (const float*)d_in[16];
  const float* rnn2_gc  = (const float*)d_in[17];
  const float* rnn2_bc  = (const float*)d_in[18];
  const float* proj_w   = (const float*)d_in[19];
  const float* proj_b   = (const float*)d_in[20];
  float* out = (float*)d_out;

  char* w = (char*)d_ws;
  f16* cellin = (f16*)w;      w += (size_t)24576*800*2;
  f16* wxT1   = (f16*)w;      w += (size_t)4096*800*2;
  f16* whT1   = (f16*)w;      w += (size_t)4096*1024*2;
  f16* w2T    = (f16*)w;      w += (size_t)4096*2048*2;
  f16* projT  = (f16*)w;      w += 262144;
  f16* H2all  = (f16*)w;      w += (size_t)769*32768*2;
  f16* h1buf  = (f16*)w;      w += 262144;   // 4 slots x 32x1024 f16
  f16* h2buf  = (f16*)w;      w += 131072;   // 2 slots
  float* zbuf1 = (float*)w;   w += (size_t)32*4096*4;
  float* zbuf2 = (float*)w;   w += (size_t)32*4096*4;
  unsigned* tags = (unsigned*)w; w += 28672;
  const size_t need = (size_t)((char*)w - (char*)d_ws);
  if (ws_size < need){
    k_ws_report<<<(out_size + 255)/256, 256, 0, stream>>>(out, out_size, (float)(ws_size >> 20));
    return;
  }

  (void)hipMemsetAsync(tags, 0, 28672, stream);
  (void)hipMemsetAsync(h1buf, 0, 262144, stream);
  (void)hipMemsetAsync(h2buf, 0, 131072, stream);

  k_transpose_f16<<<dim3(4096/32, 25), 256, 0, stream>>>(rnn1_wx, wxT1, 800, 4096, 800, 0);
  k_transpose_f16<<<dim3(4096/32, 32), 256, 0, stream>>>(rnn1_wh, whT1, 1024, 4096, 1024, 0);
  k_transpose_f16<<<dim3(4096/32, 32), 256, 0, stream>>>(rnn2_wx, w2T, 1024, 4096, 2048, 0);
  k_transpose_f16<<<dim3(4096/32, 32), 256, 0, stream>>>(rnn2_wh, w2T, 1024, 4096, 2048, 1024);
  k_transpose_f16<<<dim3(3, 49), 256, 0, stream>>>(proj_w, projT, 1568, 80, 1568, 0);
  k_prenet<<<768, 256, 0, stream>>>(decoder, pre_w1, pre_w2, cellin);
  k_durfill<<<768, 256, 0, stream>>>(duration, cellin);
  k_recurrence<<<256, 512, 0, stream>>>(cellin, wxT1, whT1, w2T, H2all, h1buf, h2buf,
      zbuf1, zbuf2, tags,
      rnn1_b, rnn1_g, rnn1_bn, rnn1_gc, rnn1_bc,
      rnn2_b, rnn2_g, rnn2_bn, rnn2_gc, rnn2_bc);
  k_proj<<<768, 256, 0, stream>>>(H2all, cellin, projT, proj_b, out);
}